// Round 1
// baseline (269.892 us; speedup 1.0000x reference)
//
#include <hip/hip_runtime.h>
#include <hip/hip_bf16.h>
#include <math.h>

#define B_TOT 16384
#define T_DIM 64
#define D_DIM 32
#define K_DIM 32
#define H_DIM 32
#define L_DIM 16

// ---------- prep: transpose basis [K][T] -> basisT [T][K] ----------
__global__ void prep_transpose(const float* __restrict__ basis, float* __restrict__ basisT) {
    int i = blockIdx.x * blockDim.x + threadIdx.x;  // over K*T
    if (i < K_DIM * T_DIM) {
        int k = i / T_DIM, t = i % T_DIM;
        basisT[t * K_DIM + k] = basis[i];
    }
}

// ---------- K1: coeffs[b][k][d] (bf16) = sum_t basisT[t][k]*sample[b][t][d] ----------
// block: 256 thr = 8 b * 32 d. basisT reads are wave-uniform -> s_load + v_fmac(s,v,v).
__global__ __launch_bounds__(256) void proj_kernel(const float* __restrict__ sample,
                                                   const float* __restrict__ basisT,
                                                   __hip_bfloat16* __restrict__ coeffs) {
    __shared__ float smp[8 * T_DIM * D_DIM];  // 64 KB
    const int tid = threadIdx.x;
    const long b0 = (long)blockIdx.x * 8;

    // stage 8 batch elements = 16384 floats = 4096 float4, fully coalesced
    const float4* src = reinterpret_cast<const float4*>(sample + b0 * (T_DIM * D_DIM));
    float4* dst = reinterpret_cast<float4*>(smp);
#pragma unroll
    for (int i = 0; i < 16; ++i) dst[tid + i * 256] = src[tid + i * 256];
    __syncthreads();

    const int bi = tid >> 5, d = tid & 31;
    float acc[K_DIM];
#pragma unroll
    for (int k = 0; k < K_DIM; ++k) acc[k] = 0.f;

    const float* sp = smp + bi * (T_DIM * D_DIM) + d;
#pragma unroll 4
    for (int t = 0; t < T_DIM; ++t) {
        float sv = sp[t * D_DIM];                 // lanes d contiguous: conflict-free
        const float* bt = basisT + t * K_DIM;     // uniform address -> scalar loads
#pragma unroll
        for (int k = 0; k < K_DIM; ++k) acc[k] = fmaf(bt[k], sv, acc[k]);
    }

    __hip_bfloat16* cp = coeffs + (b0 + bi) * (K_DIM * D_DIM) + d;
#pragma unroll
    for (int k = 0; k < K_DIM; ++k) cp[k * D_DIM] = __float2bfloat16(acc[k]);
}

// ---------- K2: per (b,k): MLP(GELU exact) + LayerNorm, all in registers ----------
// wave = 64 b's at one k (readfirstlane) -> W1/W2/b1/b2/gamma/beta via scalar loads.
__global__ __launch_bounds__(256) void mlp_kernel(const __hip_bfloat16* __restrict__ coeffs,
                                                  const float* __restrict__ W1,
                                                  const float* __restrict__ b1,
                                                  const float* __restrict__ W2,
                                                  const float* __restrict__ b2,
                                                  const float* __restrict__ gamma,
                                                  const float* __restrict__ beta,
                                                  float* __restrict__ out) {
    const int tid = threadIdx.x;
    const int lane = tid & 63;
    const int wv = tid >> 6;
    const int bchunk = blockIdx.x >> 3;
    const int kgrp = blockIdx.x & 7;
    int k = kgrp * 4 + wv;
    k = __builtin_amdgcn_readfirstlane(k);  // force wave-uniform -> s_load for weights
    const long b = (long)bchunk * 64 + lane;

    // load coeffs[b][k][0:32] (64 B contiguous per lane)
    const uint4* cp4 = reinterpret_cast<const uint4*>(coeffs + (b * K_DIM + k) * D_DIM);
    float cv[D_DIM];
#pragma unroll
    for (int q = 0; q < 4; ++q) {
        uint4 u = cp4[q];
        unsigned int uu[4] = {u.x, u.y, u.z, u.w};
#pragma unroll
        for (int j = 0; j < 4; ++j) {
            cv[q * 8 + j * 2 + 0] = __uint_as_float(uu[j] << 16);
            cv[q * 8 + j * 2 + 1] = __uint_as_float(uu[j] & 0xffff0000u);
        }
    }

    // MLP layer 1: h = coeffs @ W1[k] + b1[k]
    const float* w1p = W1 + k * (D_DIM * H_DIM);
    const float* b1p = b1 + k * H_DIM;
    float h[H_DIM];
#pragma unroll
    for (int j = 0; j < H_DIM; ++j) h[j] = b1p[j];
#pragma unroll 4
    for (int d = 0; d < D_DIM; ++d) {
        const float* wr = w1p + d * H_DIM;  // uniform -> s_load
        float c = cv[d];
#pragma unroll
        for (int j = 0; j < H_DIM; ++j) h[j] = fmaf(c, wr[j], h[j]);
    }

    // exact GELU: 0.5*x*(1+erf(x/sqrt(2)))
#pragma unroll
    for (int j = 0; j < H_DIM; ++j) {
        float u = h[j];
        h[j] = 0.5f * u * (1.0f + erff(u * 0.70710678118654752f));
    }

    // MLP layer 2: z = h @ W2[k] + b2[k]
    const float* w2p = W2 + k * (H_DIM * L_DIM);
    const float* b2p = b2 + k * L_DIM;
    float z[L_DIM];
#pragma unroll
    for (int l = 0; l < L_DIM; ++l) z[l] = b2p[l];
#pragma unroll 4
    for (int hh = 0; hh < H_DIM; ++hh) {
        const float* wr = w2p + hh * L_DIM;  // uniform -> s_load
        float hv = h[hh];
#pragma unroll
        for (int l = 0; l < L_DIM; ++l) z[l] = fmaf(hv, wr[l], z[l]);
    }

    // LayerNorm over L=16, thread-local
    float mu = 0.f;
#pragma unroll
    for (int l = 0; l < L_DIM; ++l) mu += z[l];
    mu *= (1.0f / L_DIM);
    float var = 0.f;
#pragma unroll
    for (int l = 0; l < L_DIM; ++l) { float dz = z[l] - mu; var = fmaf(dz, dz, var); }
    var *= (1.0f / L_DIM);
    float rstd = rsqrtf(var + 1e-5f);

    float4 o[4];
    float* of = reinterpret_cast<float*>(o);
#pragma unroll
    for (int l = 0; l < L_DIM; ++l) of[l] = fmaf(gamma[l] * rstd, z[l] - mu, beta[l]);

    float4* op = reinterpret_cast<float4*>(out + (b * K_DIM + k) * L_DIM);
#pragma unroll
    for (int q = 0; q < 4; ++q) op[q] = o[q];
}

extern "C" void kernel_launch(void* const* d_in, const int* in_sizes, int n_in,
                              void* d_out, int out_size, void* d_ws, size_t ws_size,
                              hipStream_t stream) {
    const float* sample = (const float*)d_in[0];
    const float* basis  = (const float*)d_in[1];
    const float* W1     = (const float*)d_in[2];
    const float* b1     = (const float*)d_in[3];
    const float* W2     = (const float*)d_in[4];
    const float* b2     = (const float*)d_in[5];
    const float* gamma  = (const float*)d_in[6];
    const float* beta   = (const float*)d_in[7];
    float* out = (float*)d_out;

    float* basisT = (float*)d_ws;                                      // 8 KB
    __hip_bfloat16* coeffs = (__hip_bfloat16*)((char*)d_ws + 32768);   // 32 MB

    prep_transpose<<<8, 256, 0, stream>>>(basis, basisT);
    proj_kernel<<<B_TOT / 8, 256, 0, stream>>>(sample, basisT, coeffs);
    mlp_kernel<<<(B_TOT / 64) * 8, 256, 0, stream>>>(coeffs, W1, b1, W2, b2, gamma, beta, out);
}

// Round 2
// 266.653 us; speedup vs baseline: 1.0121x; 1.0121x over previous
//
#include <hip/hip_runtime.h>
#include <hip/hip_bf16.h>
#include <math.h>

#define B_TOT 16384
#define T_DIM 64
#define D_DIM 32
#define K_DIM 32
#define H_DIM 32
#define L_DIM 16
#define KBD (B_TOT * D_DIM)  // 524288: stride of k in coeffs[K][B][D]

// ---------- prep: transpose basis [K][T] -> basisT [T][K] (tiny) ----------
__global__ void prep_transpose(const float* __restrict__ basis, float* __restrict__ basisT) {
    int i = blockIdx.x * blockDim.x + threadIdx.x;
    if (i < K_DIM * T_DIM) {
        int k = i / T_DIM, t = i % T_DIM;
        basisT[t * K_DIM + k] = basis[i];
    }
}

// ---------- K1: coeffs[k][b][d] (bf16) = sum_t basisT[t][k]*sample[b][t][d] ----------
// No LDS, no barriers: stream sample (lanes d contiguous -> coalesced),
// basisT rows are uniform addresses -> s_load + v_fmac(s,v,v). 32 acc VGPRs.
__global__ __launch_bounds__(256) void proj_kernel(const float* __restrict__ sample,
                                                   const float* __restrict__ basisT,
                                                   __hip_bfloat16* __restrict__ coeffs) {
    const int tid = threadIdx.x;
    const int bi = tid >> 5, d = tid & 31;
    const long b = (long)blockIdx.x * 8 + bi;

    float acc[K_DIM];
#pragma unroll
    for (int k = 0; k < K_DIM; ++k) acc[k] = 0.f;

    const float* sp = sample + b * (T_DIM * D_DIM) + d;
#pragma unroll 2
    for (int t = 0; t < T_DIM; ++t) {
        float sv = sp[t * D_DIM];               // coalesced stream, read once
        const float* bt = basisT + t * K_DIM;   // uniform -> scalar loads
#pragma unroll
        for (int k = 0; k < K_DIM; ++k) acc[k] = fmaf(bt[k], sv, acc[k]);
    }

    // [K][B][D] layout: per k, a wave writes 2x contiguous 64B chunks
    __hip_bfloat16* cp = coeffs + b * D_DIM + d;
#pragma unroll
    for (int k = 0; k < K_DIM; ++k) cp[(long)k * KBD] = __float2bfloat16(acc[k]);
}

// ---------- branch-free exact-GELU (erf via A&S 7.1.26, |eps| <= 1.5e-7) ----------
__device__ __forceinline__ float gelu_exact(float x) {
    const float iSqrt2 = 0.70710678118654752f;
    float y = x * iSqrt2;
    float ay = fabsf(y);
    float t = __builtin_amdgcn_rcpf(fmaf(0.3275911f, ay, 1.0f));
    float p = fmaf(fmaf(fmaf(fmaf(1.061405429f, t, -1.453152027f),
                             t, 1.421413741f),
                        t, -0.284496736f),
                   t, 0.254829592f) * t;
    float e = 1.0f - p * __expf(-ay * ay);
    e = copysignf(e, y);
    return 0.5f * x * (1.0f + e);
}

// ---------- K2: per (b,k) MLP + LayerNorm; k is BLOCK-uniform ----------
// blockIdx.x>>6 = k (guaranteed scalar weight loads); 256 b's per block.
// coeffs reads are lane-consecutive 64B -> fully coalesced.
__global__ __launch_bounds__(256) void mlp_kernel(const __hip_bfloat16* __restrict__ coeffs,
                                                  const float* __restrict__ W1,
                                                  const float* __restrict__ b1,
                                                  const float* __restrict__ W2,
                                                  const float* __restrict__ b2,
                                                  const float* __restrict__ gamma,
                                                  const float* __restrict__ beta,
                                                  float* __restrict__ out) {
    const int tid = threadIdx.x;
    const int k = blockIdx.x >> 6;                       // block-uniform
    const long b = (long)(blockIdx.x & 63) * 256 + tid;

    // coeffs[k][b][0:32]: 4x uint4, lane-contiguous
    const uint4* cp4 = reinterpret_cast<const uint4*>(coeffs + (long)k * KBD + b * D_DIM);
    float cv[D_DIM];
#pragma unroll
    for (int q = 0; q < 4; ++q) {
        uint4 u = cp4[q];
        unsigned int uu[4] = {u.x, u.y, u.z, u.w};
#pragma unroll
        for (int j = 0; j < 4; ++j) {
            cv[q * 8 + j * 2 + 0] = __uint_as_float(uu[j] << 16);
            cv[q * 8 + j * 2 + 1] = __uint_as_float(uu[j] & 0xffff0000u);
        }
    }

    // layer 1: h = cv @ W1[k] + b1[k]   (weights: scalar loads)
    const float* w1p = W1 + k * (D_DIM * H_DIM);
    const float* b1p = b1 + k * H_DIM;
    float h[H_DIM];
#pragma unroll
    for (int j = 0; j < H_DIM; ++j) h[j] = b1p[j];
#pragma unroll 4
    for (int d = 0; d < D_DIM; ++d) {
        const float* wr = w1p + d * H_DIM;
        float c = cv[d];
#pragma unroll
        for (int j = 0; j < H_DIM; ++j) h[j] = fmaf(c, wr[j], h[j]);
    }

#pragma unroll
    for (int j = 0; j < H_DIM; ++j) h[j] = gelu_exact(h[j]);

    // layer 2: z = h @ W2[k] + b2[k]
    const float* w2p = W2 + k * (H_DIM * L_DIM);
    const float* b2p = b2 + k * L_DIM;
    float z[L_DIM];
#pragma unroll
    for (int l = 0; l < L_DIM; ++l) z[l] = b2p[l];
#pragma unroll 4
    for (int hh = 0; hh < H_DIM; ++hh) {
        const float* wr = w2p + hh * L_DIM;
        float hv = h[hh];
#pragma unroll
        for (int l = 0; l < L_DIM; ++l) z[l] = fmaf(hv, wr[l], z[l]);
    }

    // LayerNorm over L=16 (thread-local)
    float mu = 0.f;
#pragma unroll
    for (int l = 0; l < L_DIM; ++l) mu += z[l];
    mu *= (1.0f / L_DIM);
    float var = 0.f;
#pragma unroll
    for (int l = 0; l < L_DIM; ++l) { float dz = z[l] - mu; var = fmaf(dz, dz, var); }
    var *= (1.0f / L_DIM);
    float rstd = rsqrtf(var + 1e-5f);

    float4 o[4];
    float* of = reinterpret_cast<float*>(o);
#pragma unroll
    for (int l = 0; l < L_DIM; ++l) of[l] = fmaf(gamma[l] * rstd, z[l] - mu, beta[l]);

    // out[b][k][0:16]: 64B contiguous per lane (best possible given k-blocking)
    float4* op = reinterpret_cast<float4*>(out + (b * K_DIM + k) * L_DIM);
#pragma unroll
    for (int q = 0; q < 4; ++q) op[q] = o[q];
}

extern "C" void kernel_launch(void* const* d_in, const int* in_sizes, int n_in,
                              void* d_out, int out_size, void* d_ws, size_t ws_size,
                              hipStream_t stream) {
    const float* sample = (const float*)d_in[0];
    const float* basis  = (const float*)d_in[1];
    const float* W1     = (const float*)d_in[2];
    const float* b1     = (const float*)d_in[3];
    const float* W2     = (const float*)d_in[4];
    const float* b2     = (const float*)d_in[5];
    const float* gamma  = (const float*)d_in[6];
    const float* beta   = (const float*)d_in[7];
    float* out = (float*)d_out;

    float* basisT = (float*)d_ws;                                      // 8 KB
    __hip_bfloat16* coeffs = (__hip_bfloat16*)((char*)d_ws + 32768);   // 32 MB

    prep_transpose<<<8, 256, 0, stream>>>(basis, basisT);
    proj_kernel<<<B_TOT / 8, 256, 0, stream>>>(sample, basisT, coeffs);
    mlp_kernel<<<(B_TOT / 256) * K_DIM, 256, 0, stream>>>(coeffs, W1, b1, W2, b2, gamma, beta, out);
}